// Round 7
// baseline (167.390 us; speedup 1.0000x reference)
//
#include <hip/hip_runtime.h>

// bicon_loss R13: resubmit of R12 (container died twice - infra, not kernel).
// Theory unchanged: R11 proved per-wave MLP is not the limiter (forced
// 25-outstanding-load burst was timing-flat); the system drains the request
// stream at ~4.3 TB/s. Lever: issue fewer request bytes.
//   - each thread marches a 4-row strip; vertical neighbors (y+-1) from
//     register rotation (pp5..pp7 kept, pn0..pn2 prefetched);
//   - horizontal neighbors (x+-1) from __shfl_up/down(1) of sigmoid quads;
//     wave-edge lanes patch ONE element via 1-lane scalar load; image-edge
//     elements lm/rm-masked (strip-wrap lanes inside a wave are exactly
//     image edges -> masked garbage, correct by construction).
// 100 -> 74 B/pixel request bytes (-26%), sigmoid count per row ~halved.
// Changes vs R12: unused var removed; lambda -> unrolled loop with
// compile-time fullPrefetch flag (no runtime-indexed state risk).
// Prediction: dur 46 -> ~34us; flat => request-rate theory falsified.

#define EPSF 1e-7f

constexpr int B_ = 16, H = 352, W = 352;
constexpr int HW = H * W;          // 123904
constexpr int W4 = W / 4;          // 88 quads per row
constexpr int RPT = 4;             // rows per thread
constexpr int STRIPS = H / RPT;    // 88
constexpr int SPB = STRIPS * W4;   // 7744 threads per batch image
constexpr int NT = B_ * SPB;       // 123904 threads total
constexpr int BLK = 256;
constexpr int NBLK = NT / BLK;     // 484

typedef float f4 __attribute__((ext_vector_type(4)));
typedef int   i4 __attribute__((ext_vector_type(4)));

__device__ __forceinline__ float rcpf(float x) { return __builtin_amdgcn_rcpf(x); }
__device__ __forceinline__ float sigf(float x) { return rcpf(1.0f + __expf(-x)); }

__device__ __forceinline__ f4 sigmoid4(f4 x) {
    f4 r;
    r.x = rcpf(1.0f + __expf(-x.x));
    r.y = rcpf(1.0f + __expf(-x.y));
    r.z = rcpf(1.0f + __expf(-x.z));
    r.w = rcpf(1.0f + __expf(-x.w));
    return r;
}
__device__ __forceinline__ f4 max4(f4 a, f4 b) {
    f4 r; r.x=fmaxf(a.x,b.x); r.y=fmaxf(a.y,b.y); r.z=fmaxf(a.z,b.z); r.w=fmaxf(a.w,b.w); return r;
}
__device__ __forceinline__ f4 min4(f4 a, f4 b) {
    f4 r; r.x=fminf(a.x,b.x); r.y=fminf(a.y,b.y); r.z=fminf(a.z,b.z); r.w=fminf(a.w,b.w); return r;
}
__device__ __forceinline__ f4 sel4(i4 q, f4 a, f4 b) {
    f4 r; r.x=q.x?a.x:b.x; r.y=q.y?a.y:b.y; r.z=q.z?a.z:b.z; r.w=q.w?a.w:b.w; return r;
}
__device__ __forceinline__ f4 ld4(const float* p) { return *(const f4*)p; }
__device__ __forceinline__ i4 ldi4(const int* p)  { return *(const i4*)p; }

// shifted-quad builders from already-sigmoided neighbor quads.
// shiftR: value at x-1 (DX=+1 dirs). shiftL: value at x+1 (DX=-1 dirs).
__device__ __forceinline__ f4 shiftR4(f4 p, float fixL, bool isLane0) {
    float left = __shfl_up(p.w, 1, 64);
    if (isLane0) left = fixL;        // wave-edge patch (image edge lm-masked)
    f4 r; r.x = left; r.y = p.x; r.z = p.y; r.w = p.z; return r;
}
__device__ __forceinline__ f4 shiftL4(f4 p, float fixR, bool isLane63) {
    float right = __shfl_down(p.x, 1, 64);
    if (isLane63) right = fixR;
    f4 r; r.x = p.y; r.y = p.z; r.z = p.w; r.w = right; return r;
}

__device__ __forceinline__ float finish_pixel(float glo, float pmin, int sc,
                                              float t, float cp, float ba, float bb) {
    const float edge = (sc < 8 && sc > 0) ? 1.0f : 0.0f;
    float dec = glo * (1.0f - edge) + (1.0f - pmin) * edge;
    dec = fminf(fmaxf(dec, EPSF), 1.0f - EPSF);
    const float de = -(t * __logf(dec) + (1.0f - t) * __logf(1.0f - dec));
    return de - 0.8f * __logf(cp) - 0.2f * (__logf(ba) + __logf(bb));
}

__global__ __launch_bounds__(BLK) void bicon_r13_main(
    const float* __restrict__ c_map,    // [B,8,H,W]
    const float* __restrict__ target,   // [B,1,H,W]
    const int*   __restrict__ con,      // [B,8,H,W] in {0,1}
    float* __restrict__ ws)             // [NBLK] partial sums
{
    const int tid   = blockIdx.x * BLK + threadIdx.x;   // < NT exactly
    const int b     = tid / SPB;
    const int rem   = tid - b * SPB;
    const int strip = rem / W4;
    const int xq    = rem - strip * W4;
    const int x0    = xq * 4;
    const int y0    = strip * RPT;
    const int lane  = threadIdx.x & 63;

    const float* __restrict__ cmb = c_map + (size_t)b * 8 * HW;
    const int*   __restrict__ cnb = con   + (size_t)b * 8 * HW;
    const float* __restrict__ tb  = target + (size_t)b * HW;

    const float lm = (xq == 0)      ? 0.0f : 1.0f;  // left image edge  (DX=+1)
    const float rm = (xq == W4 - 1) ? 0.0f : 1.0f;  // right image edge (DX=-1)

    // ---------------- prologue: rows y0-1 (ch 5,6,7) and y0 (all 8) --------
    const int ypr = (y0 > 0) ? y0 - 1 : 0;          // clamped; tm masks y==0
    f4 pp5 = sigmoid4(ld4(cmb + 5 * HW + ypr * W + x0));
    f4 pp6 = sigmoid4(ld4(cmb + 6 * HW + ypr * W + x0));
    f4 pp7 = sigmoid4(ld4(cmb + 7 * HW + ypr * W + x0));
    f4 p0 = sigmoid4(ld4(cmb + 0 * HW + y0 * W + x0));
    f4 p1 = sigmoid4(ld4(cmb + 1 * HW + y0 * W + x0));
    f4 p2 = sigmoid4(ld4(cmb + 2 * HW + y0 * W + x0));
    f4 p3 = sigmoid4(ld4(cmb + 3 * HW + y0 * W + x0));
    f4 p4 = sigmoid4(ld4(cmb + 4 * HW + y0 * W + x0));
    f4 p5 = sigmoid4(ld4(cmb + 5 * HW + y0 * W + x0));
    f4 p6 = sigmoid4(ld4(cmb + 6 * HW + y0 * W + x0));
    f4 p7 = sigmoid4(ld4(cmb + 7 * HW + y0 * W + x0));

    float part = 0.0f;

    #pragma unroll
    for (int r = 0; r < RPT; ++r) {
        const bool fullPrefetch = (r != RPT - 1);
        const int y  = y0 + r;
        const int yn = (y + 1 < H) ? y + 1 : y;     // clamped; bm masks y==H-1
        const int ypc = (y > 0) ? y - 1 : 0;        // clamped; tm masks y==0
        const float* cyn = cmb + yn * W + x0;

        // next-row prefetch (these become cur row next iteration)
        const f4 cn0 = ld4(cyn + 0 * HW);
        const f4 cn1 = ld4(cyn + 1 * HW);
        const f4 cn2 = ld4(cyn + 2 * HW);
        f4 cn3{}, cn4{}, cn5{}, cn6{}, cn7{};
        if (fullPrefetch) {
            cn3 = ld4(cyn + 3 * HW);
            cn4 = ld4(cyn + 4 * HW);
            cn5 = ld4(cyn + 5 * HW);
            cn6 = ld4(cyn + 6 * HW);
            cn7 = ld4(cyn + 7 * HW);
        }
        const int* qy = cnb + y * W + x0;
        const i4 q0 = ldi4(qy + 0 * HW);
        const i4 q1 = ldi4(qy + 1 * HW);
        const i4 q2 = ldi4(qy + 2 * HW);
        const i4 q3 = ldi4(qy + 3 * HW);
        const i4 q4 = ldi4(qy + 4 * HW);
        const i4 q5 = ldi4(qy + 5 * HW);
        const i4 q6 = ldi4(qy + 6 * HW);
        const i4 q7 = ldi4(qy + 7 * HW);
        const f4 t4 = ld4(tb + y * W + x0);

        // wave-edge fixups: ONE element each, 1 active lane, L1/L2-hot lines.
        float fA = 0.f, fB = 0.f, fC = 0.f, fD = 0.f, fE = 0.f, fF = 0.f;
        if (lane == 0) {
            const int xl = (xq == 0) ? x0 : x0 - 1;          // lm-masked if xq==0
            fA = sigf(cmb[7 * HW + ypc * W + xl]);           // dir0 src ch7@y-1
            fB = sigf(cmb[4 * HW + y   * W + xl]);           // dir3 src ch4@y
            fC = sigf(cmb[2 * HW + yn  * W + xl]);           // dir5 src ch2@y+1
        } else if (lane == 63) {
            const int xr = (xq == W4 - 1) ? x0 + 3 : x0 + 4; // rm-masked if edge
            fD = sigf(cmb[5 * HW + ypc * W + xr]);           // dir2 src ch5@y-1
            fE = sigf(cmb[3 * HW + y   * W + xr]);           // dir4 src ch3@y
            fF = sigf(cmb[0 * HW + yn  * W + xr]);           // dir7 src ch0@y+1
        }

        const f4 pn0 = sigmoid4(cn0);
        const f4 pn1 = sigmoid4(cn1);
        const f4 pn2 = sigmoid4(cn2);

        const float tm = (y == 0)     ? 0.0f : 1.0f;
        const float bm = (y == H - 1) ? 0.0f : 1.0f;

        // shifted neighbor quads, all from registers/shuffles
        const f4 s0 = shiftR4(pp7, fA, lane == 0);   // ch7 @ (y-1, x-1)
        const f4 s1 = pp6;                           // ch6 @ (y-1, x  )
        const f4 s2 = shiftL4(pp5, fD, lane == 63);  // ch5 @ (y-1, x+1)
        const f4 s3 = shiftR4(p4,  fB, lane == 0);   // ch4 @ (y,   x-1)
        const f4 s4 = shiftL4(p3,  fE, lane == 63);  // ch3 @ (y,   x+1)
        const f4 s5 = shiftR4(pn2, fC, lane == 0);   // ch2 @ (y+1, x-1)
        const f4 s6 = pn1;                           // ch1 @ (y+1, x  )
        const f4 s7 = shiftL4(pn0, fF, lane == 63);  // ch0 @ (y+1, x+1)

        f4 conprod = {1.f,1.f,1.f,1.f};
        f4 biA     = {1.f,1.f,1.f,1.f};
        f4 biB     = {1.f,1.f,1.f,1.f};
        f4 glo     = {-1e30f,-1e30f,-1e30f,-1e30f};
        f4 pmin    = { 1e30f, 1e30f, 1e30f, 1e30f};

#define DIR(P, Q, S, DX, RMASK, BI) {                                         \
        f4 s = (S);                                                           \
        s *= (RMASK);                                                         \
        if ((DX) == 1)  s.x *= lm;                                            \
        if ((DX) == -1) s.w *= rm;                                            \
        const f4 v = (P) * s;                                                 \
        glo  = max4(glo,  v);                                                 \
        pmin = min4(pmin, v);                                                 \
        conprod *= sel4((Q), (P), 1.0f - (P));                                \
        BI *= sel4((Q), max4(v, (f4){EPSF,EPSF,EPSF,EPSF}), 1.0f - v);        \
    }
        DIR(p0, q0, s0,  1, tm, biA)
        DIR(p1, q1, s1,  0, tm, biA)
        DIR(p2, q2, s2, -1, tm, biA)
        DIR(p3, q3, s3,  1, 1.0f, biA)
        DIR(p4, q4, s4, -1, 1.0f, biB)
        DIR(p5, q5, s5,  1, bm, biB)
        DIR(p6, q6, s6,  0, bm, biB)
        DIR(p7, q7, s7, -1, bm, biB)
#undef DIR

        const i4 sc = q0 + q1 + q2 + q3 + q4 + q5 + q6 + q7;

        part += finish_pixel(glo.x, pmin.x, sc.x, t4.x, conprod.x, biA.x, biB.x)
              + finish_pixel(glo.y, pmin.y, sc.y, t4.y, conprod.y, biA.y, biB.y)
              + finish_pixel(glo.z, pmin.z, sc.z, t4.z, conprod.z, biA.z, biB.z)
              + finish_pixel(glo.w, pmin.w, sc.w, t4.w, conprod.w, biA.w, biB.w);

        // rotate rows
        pp5 = p5; pp6 = p6; pp7 = p7;
        p0 = pn0; p1 = pn1; p2 = pn2;
        if (fullPrefetch) {
            p3 = sigmoid4(cn3);
            p4 = sigmoid4(cn4);
            p5 = sigmoid4(cn5);
            p6 = sigmoid4(cn6);
            p7 = sigmoid4(cn7);
        }
    }

    // wave64 shuffle reduction
    #pragma unroll
    for (int off = 32; off > 0; off >>= 1)
        part += __shfl_down(part, off, 64);

    __shared__ float wsum[4];
    const int wid = threadIdx.x >> 6;
    if (lane == 0) wsum[wid] = part;
    __syncthreads();
    if (threadIdx.x == 0) {
        ws[blockIdx.x] = wsum[0] + wsum[1] + wsum[2] + wsum[3];  // plain store
    }
}

// Stage 2: one block sums the NBLK partials and writes the scalar output.
__global__ __launch_bounds__(256) void bicon_r13_reduce(
    const float* __restrict__ ws, float* __restrict__ out)
{
    float s = 0.0f;
    for (int i = threadIdx.x; i < NBLK; i += 256) s += ws[i];
    #pragma unroll
    for (int off = 32; off > 0; off >>= 1)
        s += __shfl_down(s, off, 64);
    __shared__ float wsum[4];
    const int lane = threadIdx.x & 63;
    const int wid  = threadIdx.x >> 6;
    if (lane == 0) wsum[wid] = s;
    __syncthreads();
    if (threadIdx.x == 0) out[0] = wsum[0] + wsum[1] + wsum[2] + wsum[3];
}

extern "C" void kernel_launch(void* const* d_in, const int* in_sizes, int n_in,
                              void* d_out, int out_size, void* d_ws, size_t ws_size,
                              hipStream_t stream) {
    const float* c_map  = (const float*)d_in[0];
    const float* target = (const float*)d_in[1];
    const int*   con    = (const int*)d_in[2];
    float* out = (float*)d_out;
    float* ws  = (float*)d_ws;   // NBLK floats

    bicon_r13_main<<<NBLK, BLK, 0, stream>>>(c_map, target, con, ws);
    bicon_r13_reduce<<<1, 256, 0, stream>>>(ws, out);
}